// Round 9
// baseline (110.394 us; speedup 1.0000x reference)
//
#include <hip/hip_runtime.h>

#define NMODE 8
#define NPSI  512
#define REP   2   // DIAGNOSTIC round: execute the full computation twice.
                  // Inputs are laundered per pass (no CSE of pass 2 vs pass 1)
                  // AND each pass's outputs are kept live via asm-use (no DCE of
                  // pass 1 -- this was Round 8's bug). Output value unchanged.
                  // Purpose: Delta(bench) vs Round 6 == one kernel-pass time, and
                  // at ~2x duration eik should enter the rocprof top-5 with full
                  // counters. Revert to single pass next round.

// 1 particle per thread; 256 threads/block; 2048 blocks. No LDS: tables
// (16KB+2KB) are L1/L2-resident, taps gathered from global. Per-mode
// constants on the scalar (SGPR) path. Branch trig via rotation identity.
__global__ __launch_bounds__(256) void eik_kernel(
    const float* __restrict__ t_p,
    const float* __restrict__ r_p,
    const float* __restrict__ vp_p,
    const float* __restrict__ z_p,
    const float* __restrict__ psi_p,
    const float* __restrict__ ghre_p,
    const float* __restrict__ ghim_p,
    const float* __restrict__ a0tab_p,
    const float* __restrict__ iotatab_p,
    const float* __restrict__ psi0_p,
    const float* __restrict__ psisc_p,
    const float* __restrict__ alsc_p,
    const float* __restrict__ omega_p,
    const int*   __restrict__ nmode_p,
    float* __restrict__ out,
    int npart)
{
    constexpr float R0      = 1.7f;
    constexpr float TWO_PI  = 6.28318530717958647692f;
    constexpr float INV_2PI = 0.15915494309189533577f;
    constexpr float NHL2E   = -0.72134752044448170368f; // -0.5*log2(e)

    const int i = blockIdx.x * 256 + threadIdx.x;
    if (i >= npart) return;

    // ---- particle inputs (coalesced), loaded once ----
    const float ps_in = psi_p[i];
    const float rr_in = r_p[i];
    const float zz_in = z_p[i];
    const float vp_in = vp_p[i];
    const float tval  = t_p[0];

    float o0 = 0.0f, o1 = 0.0f;

    #pragma unroll 1
    for (int rep = 0; rep < REP; ++rep) {
        // Launder inputs: formally-new SSA values each pass.
        float ps = ps_in, rr = rr_in, zz = zz_in, vp = vp_in;
        asm volatile("" : "+v"(ps), "+v"(rr), "+v"(zz), "+v"(vp));

        const float th = atan2f(zz, rr - R0);

        // ---- Catmull-Rom setup (uniform grid over [0,1], 512 pts) ----
        const float s = ps * (float)(NPSI - 1);
        int ii = (int)floorf(s);
        ii = ii < 1 ? 1 : (ii > NPSI - 3 ? NPSI - 3 : ii);
        const float tt = s - (float)ii;
        const float t2 = tt * tt, t3 = t2 * tt;
        const float w0 = 0.5f * (-t3 + 2.0f * t2 - tt);
        const float w1 = 0.5f * (3.0f * t3 - 5.0f * t2 + 2.0f);
        const float w2 = 0.5f * (-3.0f * t3 + 4.0f * t2 + tt);
        const float w3 = 0.5f * (t3 - t2);

        // ---- gather all 4 tap rows from global (L1/L2-resident tables) ----
        const float4* a0q = reinterpret_cast<const float4*>(a0tab_p);
        const int r0 = ii - 1;
        const float4 lo0 = a0q[2*(r0+0)+0], hi0 = a0q[2*(r0+0)+1];
        const float4 lo1 = a0q[2*(r0+1)+0], hi1 = a0q[2*(r0+1)+1];
        const float4 lo2 = a0q[2*(r0+2)+0], hi2 = a0q[2*(r0+2)+1];
        const float4 lo3 = a0q[2*(r0+3)+0], hi3 = a0q[2*(r0+3)+1];
        const float io0 = iotatab_p[r0+0], io1 = iotatab_p[r0+1];
        const float io2 = iotatab_p[r0+2], io3 = iotatab_p[r0+3];

        float a0v[NMODE];
        a0v[0] = w0*lo0.x + w1*lo1.x + w2*lo2.x + w3*lo3.x;
        a0v[1] = w0*lo0.y + w1*lo1.y + w2*lo2.y + w3*lo3.y;
        a0v[2] = w0*lo0.z + w1*lo1.z + w2*lo2.z + w3*lo3.z;
        a0v[3] = w0*lo0.w + w1*lo1.w + w2*lo2.w + w3*lo3.w;
        a0v[4] = w0*hi0.x + w1*hi1.x + w2*hi2.x + w3*hi3.x;
        a0v[5] = w0*hi0.y + w1*hi1.y + w2*hi2.y + w3*hi3.y;
        a0v[6] = w0*hi0.z + w1*hi1.z + w2*hi2.z + w3*hi3.z;
        a0v[7] = w0*hi0.w + w1*hi1.w + w2*hi2.w + w3*hi3.w;
        const float iotv = w0*io0 + w1*io1 + w2*io2 + w3*io3;

        const float at  = iotv * th;
        const float dyb = iotv * TWO_PI;

        float acc0a = 0.0f, acc0b = 0.0f;
        float acc1a = 0.0f, acc1b = 0.0f;

        #pragma unroll
        for (int m = 0; m < NMODE; ++m) {
            const float c0r0 = ghre_p[m*12+ 0], c0r1 = ghre_p[m*12+ 1];
            const float c1r0 = ghre_p[m*12+ 2], c1r1 = ghre_p[m*12+ 3];
            const float c2r0 = ghre_p[m*12+ 4], c2r1 = ghre_p[m*12+ 5];
            const float c3r0 = ghre_p[m*12+ 6], c3r1 = ghre_p[m*12+ 7];
            const float c4r0 = ghre_p[m*12+ 8], c4r1 = ghre_p[m*12+ 9];
            const float c5r0 = ghre_p[m*12+10], c5r1 = ghre_p[m*12+11];
            const float c0i0 = ghim_p[m*12+ 0], c0i1 = ghim_p[m*12+ 1];
            const float c1i0 = ghim_p[m*12+ 2], c1i1 = ghim_p[m*12+ 3];
            const float c2i0 = ghim_p[m*12+ 4], c2i1 = ghim_p[m*12+ 5];
            const float c3i0 = ghim_p[m*12+ 6], c3i1 = ghim_p[m*12+ 7];
            const float c4i0 = ghim_p[m*12+ 8], c4i1 = ghim_p[m*12+ 9];
            const float c5i0 = ghim_p[m*12+10], c5i1 = ghim_p[m*12+11];
            const float psi0m = psi0_p[m];
            const float ipsc  = __builtin_amdgcn_rcpf(psisc_p[m]);
            const float iasc  = __builtin_amdgcn_rcpf(alsc_p[m]);
            const float ot    = omega_p[m] * tval;
            const float nf    = (float)nmode_p[m];

            const float a0    = a0v[m];
            const float x     = (ps - psi0m) * ipsc;
            const float xx    = x * x;
            const float h20   = fmaf(4.0f, xx, -2.0f);
            const float xterm = xx * NHL2E;
            const float base  = at - a0;
            const float y1    = base * iasc;
            const float dy    = dyb * iasc;
            const float pcr   = (ot - nf * (vp - base)) * INV_2PI;
            const float dpr   = nf * iotv;

            const float snC = __builtin_amdgcn_sinf(__builtin_amdgcn_fractf(pcr));
            const float csC = __builtin_amdgcn_cosf(__builtin_amdgcn_fractf(pcr));
            const float snD = __builtin_amdgcn_sinf(__builtin_amdgcn_fractf(dpr));
            const float csD = __builtin_amdgcn_cosf(__builtin_amdgcn_fractf(dpr));
            const float pcc = csC * csD, pss = snC * snD;
            const float psc_ = snC * csD, pcs = csC * snD;
            const float csM = pcc + pss, snM = psc_ - pcs;
            const float csP = pcc - pss, snP = psc_ + pcs;

            const float pxr0 = fmaf(c3r0, h20, fmaf(c1r0, x, c0r0));
            const float pxr1 = fmaf(c3r1, h20, fmaf(c1r1, x, c0r1));
            const float pxi0 = fmaf(c3i0, h20, fmaf(c1i0, x, c0i0));
            const float pxi1 = fmaf(c3i1, h20, fmaf(c1i1, x, c0i1));
            const float er0  = fmaf(c4r0, x, c2r0);
            const float er1  = fmaf(c4r1, x, c2r1);
            const float ei0  = fmaf(c4i0, x, c2i0);
            const float ei1  = fmaf(c4i1, x, c2i1);

            #pragma unroll
            for (int k = 0; k < 3; ++k) {
                const float kf = (float)(k - 1);
                const float y  = fmaf(kf, dy, y1);
                const float cs = (k == 0) ? csM : (k == 1) ? csC : csP;
                const float sn = (k == 0) ? snM : (k == 1) ? snC : snP;
                const float yy  = y * y;
                const float g   = __builtin_amdgcn_exp2f(fmaf(yy, NHL2E, xterm));
                const float h02 = fmaf(4.0f, yy, -2.0f);
                const float pr0 = fmaf(c5r0, h02, fmaf(er0, y, pxr0));
                const float pr1 = fmaf(c5r1, h02, fmaf(er1, y, pxr1));
                const float pi0 = fmaf(c5i0, h02, fmaf(ei0, y, pxi0));
                const float pi1 = fmaf(c5i1, h02, fmaf(ei1, y, pxi1));
                const float gc = g * cs;
                const float gs = g * sn;
                acc0a = fmaf(pr0, gc, acc0a);
                acc0b = fmaf(pi0, gs, acc0b);
                acc1a = fmaf(pr1, gc, acc1a);
                acc1b = fmaf(pi1, gs, acc1b);
            }
        }

        o0 = acc0a - acc0b;
        o1 = acc1a - acc1b;
        // KEEP THIS PASS'S RESULTS LIVE (Round 8's missing piece): a formal
        // use of o0/o1 here means pass 1 is not dead code even though pass 2
        // overwrites them. Identical math both passes -> output unchanged.
        asm volatile("" :: "v"(o0), "v"(o1));
    }

    reinterpret_cast<float2*>(out)[i] = make_float2(o0, o1);
}

extern "C" void kernel_launch(void* const* d_in, const int* in_sizes, int n_in,
                              void* d_out, int out_size, void* d_ws, size_t ws_size,
                              hipStream_t stream) {
    const float* t      = (const float*)d_in[0];
    const float* r      = (const float*)d_in[1];
    const float* varphi = (const float*)d_in[2];
    const float* z      = (const float*)d_in[3];
    const float* psi    = (const float*)d_in[4];
    const float* gh_re  = (const float*)d_in[5];
    const float* gh_im  = (const float*)d_in[6];
    const float* a0t    = (const float*)d_in[7];
    const float* iot    = (const float*)d_in[8];
    const float* psi0   = (const float*)d_in[9];
    const float* psc    = (const float*)d_in[10];
    const float* asc    = (const float*)d_in[11];
    const float* omg    = (const float*)d_in[12];
    const int*   nn     = (const int*)d_in[13];
    float* out = (float*)d_out;

    const int npart  = in_sizes[1];
    const int blocks = (npart + 255) / 256;
    eik_kernel<<<blocks, 256, 0, stream>>>(t, r, varphi, z, psi, gh_re, gh_im,
                                           a0t, iot, psi0, psc, asc, omg, nn,
                                           out, npart);
}

// Round 10
// 98.125 us; speedup vs baseline: 1.1250x; 1.1250x over previous
//
#include <hip/hip_runtime.h>

#define NMODE 8
#define NPSI  512

// 1 particle per thread; 256 threads/block; 2048 blocks. No LDS: tables
// (16KB+2KB) are L1/L2-resident, taps gathered from global. Per-mode
// constants on the scalar (SGPR) path. Branch trig via rotation identity.
// Field dimension (phi, A_par) packed as 2-wide f32 vectors -> v_pk_fma_f32
// (full-rate packed FP32 on CDNA4) halves the FMA issue count of the
// polynomial + accumulate work. Coefficients gh[m][j][f] have f contiguous,
// so each coef pair is one aligned 8B scalar load.
typedef float v2f __attribute__((ext_vector_type(2)));
#define V2FMA(a, b, c) __builtin_elementwise_fma((a), (b), (c))

__global__ __launch_bounds__(256) void eik_kernel(
    const float* __restrict__ t_p,
    const float* __restrict__ r_p,
    const float* __restrict__ vp_p,
    const float* __restrict__ z_p,
    const float* __restrict__ psi_p,
    const float* __restrict__ ghre_p,
    const float* __restrict__ ghim_p,
    const float* __restrict__ a0tab_p,
    const float* __restrict__ iotatab_p,
    const float* __restrict__ psi0_p,
    const float* __restrict__ psisc_p,
    const float* __restrict__ alsc_p,
    const float* __restrict__ omega_p,
    const int*   __restrict__ nmode_p,
    float* __restrict__ out,
    int npart)
{
    constexpr float R0      = 1.7f;
    constexpr float TWO_PI  = 6.28318530717958647692f;
    constexpr float INV_2PI = 0.15915494309189533577f;
    constexpr float NHL2E   = -0.72134752044448170368f; // -0.5*log2(e)

    const int i = blockIdx.x * 256 + threadIdx.x;
    if (i >= npart) return;

    // ---- particle inputs (coalesced) ----
    const float ps   = psi_p[i];
    const float rr   = r_p[i];
    const float zz   = z_p[i];
    const float vp   = vp_p[i];
    const float tval = t_p[0];

    const float th = atan2f(zz, rr - R0);

    // ---- Catmull-Rom setup (uniform grid over [0,1], 512 pts) ----
    const float s = ps * (float)(NPSI - 1);
    int ii = (int)floorf(s);
    ii = ii < 1 ? 1 : (ii > NPSI - 3 ? NPSI - 3 : ii);
    const float tt = s - (float)ii;
    const float t2 = tt * tt, t3 = t2 * tt;
    const float w0 = 0.5f * (-t3 + 2.0f * t2 - tt);
    const float w1 = 0.5f * (3.0f * t3 - 5.0f * t2 + 2.0f);
    const float w2 = 0.5f * (-3.0f * t3 + 4.0f * t2 + tt);
    const float w3 = 0.5f * (t3 - t2);

    // ---- gather all 4 tap rows from global (L1/L2-resident tables) ----
    const float4* a0q = reinterpret_cast<const float4*>(a0tab_p);
    const int r0 = ii - 1;
    const float4 lo0 = a0q[2*(r0+0)+0], hi0 = a0q[2*(r0+0)+1];
    const float4 lo1 = a0q[2*(r0+1)+0], hi1 = a0q[2*(r0+1)+1];
    const float4 lo2 = a0q[2*(r0+2)+0], hi2 = a0q[2*(r0+2)+1];
    const float4 lo3 = a0q[2*(r0+3)+0], hi3 = a0q[2*(r0+3)+1];
    const float io0 = iotatab_p[r0+0], io1 = iotatab_p[r0+1];
    const float io2 = iotatab_p[r0+2], io3 = iotatab_p[r0+3];

    float a0v[NMODE];
    a0v[0] = w0*lo0.x + w1*lo1.x + w2*lo2.x + w3*lo3.x;
    a0v[1] = w0*lo0.y + w1*lo1.y + w2*lo2.y + w3*lo3.y;
    a0v[2] = w0*lo0.z + w1*lo1.z + w2*lo2.z + w3*lo3.z;
    a0v[3] = w0*lo0.w + w1*lo1.w + w2*lo2.w + w3*lo3.w;
    a0v[4] = w0*hi0.x + w1*hi1.x + w2*hi2.x + w3*hi3.x;
    a0v[5] = w0*hi0.y + w1*hi1.y + w2*hi2.y + w3*hi3.y;
    a0v[6] = w0*hi0.z + w1*hi1.z + w2*hi2.z + w3*hi3.z;
    a0v[7] = w0*hi0.w + w1*hi1.w + w2*hi2.w + w3*hi3.w;
    const float iotv = w0*io0 + w1*io1 + w2*io2 + w3*io3;

    const float at  = iotv * th;       // alpha at center branch (shift 0)
    const float dyb = iotv * TWO_PI;   // branch step in alpha

    v2f accA = 0.0f;   // {field0, field1} cos chain
    v2f accB = 0.0f;   // {field0, field1} sin chain

    #pragma unroll
    for (int m = 0; m < NMODE; ++m) {
        // ---- wave-uniform constants: scalar path, coef pairs as 8B loads ----
        const v2f c0r = *reinterpret_cast<const v2f*>(ghre_p + m*12 +  0);
        const v2f c1r = *reinterpret_cast<const v2f*>(ghre_p + m*12 +  2);
        const v2f c2r = *reinterpret_cast<const v2f*>(ghre_p + m*12 +  4);
        const v2f c3r = *reinterpret_cast<const v2f*>(ghre_p + m*12 +  6);
        const v2f c4r = *reinterpret_cast<const v2f*>(ghre_p + m*12 +  8);
        const v2f c5r = *reinterpret_cast<const v2f*>(ghre_p + m*12 + 10);
        const v2f c0i = *reinterpret_cast<const v2f*>(ghim_p + m*12 +  0);
        const v2f c1i = *reinterpret_cast<const v2f*>(ghim_p + m*12 +  2);
        const v2f c2i = *reinterpret_cast<const v2f*>(ghim_p + m*12 +  4);
        const v2f c3i = *reinterpret_cast<const v2f*>(ghim_p + m*12 +  6);
        const v2f c4i = *reinterpret_cast<const v2f*>(ghim_p + m*12 +  8);
        const v2f c5i = *reinterpret_cast<const v2f*>(ghim_p + m*12 + 10);
        const float psi0m = psi0_p[m];
        const float ipsc  = __builtin_amdgcn_rcpf(psisc_p[m]);
        const float iasc  = __builtin_amdgcn_rcpf(alsc_p[m]);
        const float ot    = omega_p[m] * tval;
        const float nf    = (float)nmode_p[m];

        const float a0    = a0v[m];
        const float x     = (ps - psi0m) * ipsc;
        const float xx    = x * x;
        const float h20   = fmaf(4.0f, xx, -2.0f);
        const float xterm = xx * NHL2E;
        const float base  = at - a0;
        const float y1    = base * iasc;          // y at center branch
        const float dy    = dyb * iasc;           // y step per branch
        const float pcr   = (ot - nf * (vp - base)) * INV_2PI;  // center phase, rev
        const float dpr   = nf * iotv;                          // phase step, rev

        // center + delta trig; k=+-1 by rotation identity
        const float snC = __builtin_amdgcn_sinf(__builtin_amdgcn_fractf(pcr));
        const float csC = __builtin_amdgcn_cosf(__builtin_amdgcn_fractf(pcr));
        const float snD = __builtin_amdgcn_sinf(__builtin_amdgcn_fractf(dpr));
        const float csD = __builtin_amdgcn_cosf(__builtin_amdgcn_fractf(dpr));
        const float pcc = csC * csD, pss = snC * snD;
        const float psc_ = snC * csD, pcs = csC * snD;
        const float csM = pcc + pss, snM = psc_ - pcs;
        const float csP = pcc - pss, snP = psc_ + pcs;

        // k-invariant partial polynomials (packed over fields)
        const v2f xv  = x;
        const v2f h2v = h20;
        const v2f pxr = V2FMA(c3r, h2v, V2FMA(c1r, xv, c0r));
        const v2f pxi = V2FMA(c3i, h2v, V2FMA(c1i, xv, c0i));
        const v2f er  = V2FMA(c4r, xv, c2r);
        const v2f ei  = V2FMA(c4i, xv, c2i);

        #pragma unroll
        for (int k = 0; k < 3; ++k) {
            const float kf = (float)(k - 1);
            const float y  = fmaf(kf, dy, y1);
            const float cs = (k == 0) ? csM : (k == 1) ? csC : csP;
            const float sn = (k == 0) ? snM : (k == 1) ? snC : snP;
            const float yy  = y * y;
            const float g   = __builtin_amdgcn_exp2f(fmaf(yy, NHL2E, xterm));
            const float h02 = fmaf(4.0f, yy, -2.0f);

            const v2f yv   = y;
            const v2f h02v = h02;
            const v2f gcv  = g * cs;
            const v2f gsv  = g * sn;

            const v2f pr = V2FMA(c5r, h02v, V2FMA(er, yv, pxr));
            const v2f pi = V2FMA(c5i, h02v, V2FMA(ei, yv, pxi));
            accA = V2FMA(pr, gcv, accA);
            accB = V2FMA(pi, gsv, accB);
        }
    }

    const v2f res = accA - accB;
    reinterpret_cast<float2*>(out)[i] = make_float2(res.x, res.y);
}

extern "C" void kernel_launch(void* const* d_in, const int* in_sizes, int n_in,
                              void* d_out, int out_size, void* d_ws, size_t ws_size,
                              hipStream_t stream) {
    const float* t      = (const float*)d_in[0];
    const float* r      = (const float*)d_in[1];
    const float* varphi = (const float*)d_in[2];
    const float* z      = (const float*)d_in[3];
    const float* psi    = (const float*)d_in[4];
    const float* gh_re  = (const float*)d_in[5];
    const float* gh_im  = (const float*)d_in[6];
    const float* a0t    = (const float*)d_in[7];
    const float* iot    = (const float*)d_in[8];
    const float* psi0   = (const float*)d_in[9];
    const float* psc    = (const float*)d_in[10];
    const float* asc    = (const float*)d_in[11];
    const float* omg    = (const float*)d_in[12];
    const int*   nn     = (const int*)d_in[13];
    float* out = (float*)d_out;

    const int npart  = in_sizes[1];
    const int blocks = (npart + 255) / 256;
    eik_kernel<<<blocks, 256, 0, stream>>>(t, r, varphi, z, psi, gh_re, gh_im,
                                           a0t, iot, psi0, psc, asc, omg, nn,
                                           out, npart);
}